// Round 3
// baseline (516.662 us; speedup 1.0000x reference)
//
#include <hip/hip_runtime.h>
#include <hip/hip_bf16.h>
#include <cstdint>

// Problem constants
// B=128, P=168, M=8, HIDC=50, HIDR=50, HIDS=5, CK=6, SKIP=24, HW=24
// O = P*HIDC*CK = 50400, Kdim = P*M = 1344, L = 163, PT = 6

typedef __attribute__((ext_vector_type(8))) short short8;   // 8 bf16 (4 VGPRs)
typedef __attribute__((ext_vector_type(4))) float f32x4;    // MFMA acc
typedef __attribute__((ext_vector_type(2))) float f32x2;    // packed fp32 (v_pk_fma_f32)

__device__ __forceinline__ unsigned short bf16rn(float f) {
    unsigned u = __float_as_uint(f);
    return (unsigned short)((u + 0x7FFFu + ((u >> 16) & 1u)) >> 16);
}
__device__ __forceinline__ unsigned pk2(float a, float b) {
    return ((unsigned)bf16rn(b) << 16) | (unsigned)bf16rn(a);
}
__device__ __forceinline__ uint4 pack8(float4 f0, float4 f1) {
    uint4 u;
    u.x = pk2(f0.x, f0.y); u.y = pk2(f0.z, f0.w);
    u.z = pk2(f1.x, f1.y); u.w = pk2(f1.z, f1.w);
    return u;
}
__device__ __forceinline__ float bf2f(unsigned short u) {
    return __uint_as_float((unsigned)u << 16);
}
// fast activations: v_rcp_f32 instead of precise divide (serial-chain critical)
__device__ __forceinline__ float sigmf(float x) {
    return __builtin_amdgcn_rcpf(1.f + __expf(-x));
}
__device__ __forceinline__ float tanhf_(float x) {
    return 1.f - 2.f * __builtin_amdgcn_rcpf(__expf(2.f * x) + 1.f);
}

// ---------------------------------------------------------------------------
// K1: c[b][o] = relu(xf @ wf^T + conv_b), stored bf16.  M=128, N=50400, K=1344.
// (unchanged from previous verified version)
// ---------------------------------------------------------------------------
__global__ __launch_bounds__(256, 2)
void k1_conv_gemm(const float* __restrict__ x, const float* __restrict__ w,
                  const float* __restrict__ bias, unsigned short* __restrict__ c) {
    __shared__ uint4 a_lds[8 * 129];  // A: 128 rows (b), pad->129
    __shared__ uint4 b_lds[8 * 113];  // B: 112 rows (o), pad->113
    const int tid  = threadIdx.x;
    const int n0   = blockIdx.x * 112;
    const int wave = tid >> 6, lane = tid & 63;
    const int quad = lane >> 4, m16 = lane & 15;

    f32x4 acc[2][7];
#pragma unroll
    for (int i = 0; i < 2; ++i)
#pragma unroll
        for (int j = 0; j < 7; ++j) acc[i][j] = (f32x4){0.f, 0.f, 0.f, 0.f};

    float4 pa[4][2];  // A prefetch regs
    float4 pb[4][2];  // B prefetch regs

    auto issue = [&](int kb) {
#pragma unroll
        for (int i = 0; i < 4; ++i) {
            int row = (tid >> 3) + 32 * i;
            const float* gp = x + row * 1344 + kb + (tid & 7) * 8;
            pa[i][0] = *reinterpret_cast<const float4*>(gp);
            pa[i][1] = *reinterpret_cast<const float4*>(gp + 4);
        }
#pragma unroll
        for (int i = 0; i < 4; ++i) {
            int idx = tid + 256 * i;
            if (idx < 896) {
                int row = idx >> 3;
                const float* gp = w + (size_t)(n0 + row) * 1344 + kb + (idx & 7) * 8;
                pb[i][0] = *reinterpret_cast<const float4*>(gp);
                pb[i][1] = *reinterpret_cast<const float4*>(gp + 4);
            }
        }
    };

    issue(0);
    for (int kb = 0; kb < 1344; kb += 64) {
#pragma unroll
        for (int i = 0; i < 4; ++i) {
            int idx = tid + 256 * i;
            int row = idx >> 3, ks = idx & 7;
            a_lds[ks * 129 + row] = pack8(pa[i][0], pa[i][1]);
        }
#pragma unroll
        for (int i = 0; i < 4; ++i) {
            int idx = tid + 256 * i;
            if (idx < 896) {
                int row = idx >> 3, ks = idx & 7;
                b_lds[ks * 113 + row] = pack8(pb[i][0], pb[i][1]);
            }
        }
        __syncthreads();
        if (kb + 64 < 1344) issue(kb + 64);
#pragma unroll
        for (int half = 0; half < 2; ++half) {
            const int kp = half * 4 + quad;
            short8 af[2], bfr[7];
#pragma unroll
            for (int rt = 0; rt < 2; ++rt)
                af[rt] = ((const short8*)a_lds)[kp * 129 + wave * 32 + rt * 16 + m16];
#pragma unroll
            for (int ct = 0; ct < 7; ++ct)
                bfr[ct] = ((const short8*)b_lds)[kp * 113 + ct * 16 + m16];
#pragma unroll
            for (int rt = 0; rt < 2; ++rt)
#pragma unroll
                for (int ct = 0; ct < 7; ++ct)
                    acc[rt][ct] = __builtin_amdgcn_mfma_f32_16x16x32_bf16(
                        af[rt], bfr[ct], acc[rt][ct], 0, 0, 0);
        }
        __syncthreads();
    }
#pragma unroll
    for (int ct = 0; ct < 7; ++ct) {
        int col = n0 + ct * 16 + m16;
        float bv = bias[col];
#pragma unroll
        for (int rt = 0; rt < 2; ++rt) {
#pragma unroll
            for (int r = 0; r < 4; ++r) {
                int grow = wave * 32 + rt * 16 + quad * 4 + r;
                float v = acc[rt][ct][r] + bv;
                v = fmaxf(v, 0.f);
                c[(size_t)grow * 50400 + col] = bf16rn(v);
            }
        }
    }
}

// ---------------------------------------------------------------------------
// K_PROJ: phases A+B only (proven R2 code), one block per b (128 blocks).
//   Phase A: rloc[hc][t] = sum_k c[b][...]  (LDS)
//   Phase B: gi1[t][150], gi2[pt*24+sk][15] into LDS.
//   Then coalesced LDS -> global copy-out of gi1/gi2 (float2).
// ---------------------------------------------------------------------------
__global__ __launch_bounds__(384, 1)
void k_proj(const unsigned short* __restrict__ c,
            const float* __restrict__ g1_wih, const float* __restrict__ g1_bih,
            const float* __restrict__ gs_wih, const float* __restrict__ gs_bih,
            float* __restrict__ gi1g, float* __restrict__ gi2g) {
    __shared__ float rloc[50 * 164];   // [hc][t] pad 163->164
    __shared__ __align__(8) float gi1l[163 * 150];  // [t][150] (24450 floats, even)
    __shared__ __align__(8) float gi2l[144 * 15];   // (2160 floats, even)

    const int b    = blockIdx.x;
    const int tid  = threadIdx.x;
    const int wave = tid >> 6, lane = tid & 63;

    // ---- Phase A: diagonal-sum into rloc ----
    const unsigned short* cb = c + (size_t)b * 50400;
    for (int idx = tid; idx < 8150; idx += 384) {
        int hc = idx / 163, t = idx - hc * 163;
        int base = hc * 1008 + t;
        float s = 0.f;
#pragma unroll
        for (int k = 0; k < 6; ++k) s += bf2f(cb[base + 169 * k]);
        rloc[hc * 164 + t] = s;
    }
    __syncthreads();

    // ---- Phase B: input projections gi1 / gi2 into LDS ----
    {
        const int tB   = (wave >> 1) * 64 + lane;   // 0..191
        const int half = wave & 1;
        if (tB < 163) {
            float xcol[50];
#pragma unroll
            for (int j = 0; j < 50; ++j) xcol[j] = rloc[j * 164 + tB];

            const int c0 = __builtin_amdgcn_readfirstlane(half * 75);
            const float* wbase = g1_wih + c0 * 50;
            float* gdst = &gi1l[tB * 150 + c0];
            for (int cc = 0; cc < 75; ++cc) {
                const float* wp = wbase + cc * 50;
                float acc = g1_bih[c0 + cc];
#pragma unroll
                for (int j = 0; j < 50; ++j) acc += xcol[j] * wp[j];
                gdst[cc] = acc;
            }
            if (tB >= 19) {
                const int r2 = tB - 19;  // == pt*24 + sk
                const int d0 = __builtin_amdgcn_readfirstlane(half * 8);
                const int ncol = half ? 7 : 8;
                float* g2 = &gi2l[r2 * 15];
                for (int cc = 0; cc < ncol; ++cc) {
                    const float* wp = gs_wih + (d0 + cc) * 50;
                    float acc = gs_bih[d0 + cc];
#pragma unroll
                    for (int j = 0; j < 50; ++j) acc += xcol[j] * wp[j];
                    g2[d0 + cc] = acc;
                }
            }
        }
    }
    __syncthreads();

    // ---- coalesced copy-out: gi1 (24450 floats = 12225 float2) ----
    {
        const float2* src = reinterpret_cast<const float2*>(gi1l);
        float2* dst = reinterpret_cast<float2*>(gi1g + (size_t)b * 24450);
        for (int i = tid; i < 12225; i += 384) dst[i] = src[i];
        const float2* s2 = reinterpret_cast<const float2*>(gi2l);
        float2* d2 = reinterpret_cast<float2*>(gi2g + (size_t)b * 2160);
        for (int i = tid; i < 1080; i += 384) d2[i] = s2[i];
    }
}

// ---------------------------------------------------------------------------
// K_GRU: GRU1 + GRU2 + final, one block per b, 64 threads (1 wave).
// Single-wave block => VGPR budget up to 512: the 150 pinned weight regs
// CANNOT spill (the suspected R2 bottleneck). gi rows prefetched from global
// one step ahead; h broadcast via LDS (in-order per-wave DS, no barriers).
// ---------------------------------------------------------------------------
__global__ __launch_bounds__(64, 1)
void k_gru(const float* __restrict__ gi1g, const float* __restrict__ g1_whh,
           const float* __restrict__ g1_bhh,
           const float* __restrict__ gi2g, const float* __restrict__ gs_whh,
           const float* __restrict__ gs_bhh,
           const float* __restrict__ l1_w, const float* __restrict__ l1_b,
           const float* __restrict__ x, const float* __restrict__ hw_w,
           const float* __restrict__ hw_b, float* __restrict__ out) {
    __shared__ __align__(16) float hl[64];
    __shared__ float r1l[50];
    __shared__ float hsl[120];

    const int b = blockIdx.x;
    const int lane = threadIdx.x;
    const int lc = (lane < 50) ? lane : 49;

    // ---- pin recurrence weights in VGPRs ----
    f32x2 wr2[25], wz2[25], wn2[25];
    {
        const float* wrp = g1_whh + lc * 50;          // rows 8B-aligned (200 B)
        const float* wzp = g1_whh + (50 + lc) * 50;
        const float* wnp = g1_whh + (100 + lc) * 50;
#pragma unroll
        for (int j = 0; j < 25; ++j) {
            wr2[j] = *reinterpret_cast<const f32x2*>(wrp + 2 * j);
            wz2[j] = *reinterpret_cast<const f32x2*>(wzp + 2 * j);
            wn2[j] = *reinterpret_cast<const f32x2*>(wnp + 2 * j);
        }
#pragma unroll
        for (int j = 0; j < 25; ++j) {  // keep-alive: defeat remat/spill
            asm volatile("" : "+v"(wr2[j]));
            asm volatile("" : "+v"(wz2[j]));
            asm volatile("" : "+v"(wn2[j]));
        }
    }
    const float bhr = g1_bhh[lc], bhz = g1_bhh[50 + lc], bhn = g1_bhh[100 + lc];
    hl[lane] = 0.f;
    float hcur = 0.f;

    const float* gp = gi1g + (size_t)b * 24450;
    float gir = gp[lc], giz = gp[50 + lc], gin = gp[100 + lc];
    for (int t = 0; t < 163; ++t) {
        // prefetch next step's input projection (hides L2 latency under dot)
        float ngir = 0.f, ngiz = 0.f, ngin = 0.f;
        if (t < 162) {
            const float* gq = gp + 150;
            ngir = gq[lc]; ngiz = gq[50 + lc]; ngin = gq[100 + lc];
        }
        float4 h4[12];
#pragma unroll
        for (int j4 = 0; j4 < 12; ++j4)
            h4[j4] = *reinterpret_cast<const float4*>(&hl[4 * j4]);
        f32x2 ht; ht.x = hl[48]; ht.y = hl[49];
        f32x2 ar = {0.f, 0.f}, az = {0.f, 0.f}, an = {0.f, 0.f};
#pragma unroll
        for (int j4 = 0; j4 < 12; ++j4) {
            f32x2 h0; h0.x = h4[j4].x; h0.y = h4[j4].y;
            f32x2 h1; h1.x = h4[j4].z; h1.y = h4[j4].w;
            ar += wr2[2 * j4] * h0; ar += wr2[2 * j4 + 1] * h1;
            az += wz2[2 * j4] * h0; az += wz2[2 * j4 + 1] * h1;
            an += wn2[2 * j4] * h0; an += wn2[2 * j4 + 1] * h1;
        }
        ar += wr2[24] * ht; az += wz2[24] * ht; an += wn2[24] * ht;
        float rg = sigmf(gir + bhr + ar.x + ar.y);
        float zg = sigmf(giz + bhz + az.x + az.y);
        float ng = tanhf_(gin + rg * (bhn + an.x + an.y));
        hcur = (1.f - zg) * ng + zg * hcur;
        hl[lane] = hcur;   // in-order DS: next iter's reads see this
        gir = ngir; giz = ngiz; gin = ngin;
        gp += 150;
    }
    if (lane < 50) r1l[lane] = hcur;

    // ---- GRU2: lanes 0..23, one sequence each (sk = lane), 6 steps ----
    if (lane < 24) {
        float h2[5] = {0.f, 0.f, 0.f, 0.f, 0.f};
        const float* g2base = gi2g + (size_t)b * 2160;
        for (int pt = 0; pt < 6; ++pt) {
            const float* g2 = g2base + (pt * 24 + lane) * 15;
            float gi[15];
#pragma unroll
            for (int i = 0; i < 15; ++i) gi[i] = g2[i];
            float gh[15];
#pragma unroll
            for (int i = 0; i < 15; ++i) {
                float s = gs_bhh[i];
#pragma unroll
                for (int j = 0; j < 5; ++j) s += gs_whh[i * 5 + j] * h2[j];
                gh[i] = s;
            }
#pragma unroll
            for (int u = 0; u < 5; ++u) {
                float rg = sigmf(gi[u] + gh[u]);
                float zg = sigmf(gi[5 + u] + gh[5 + u]);
                float ng = tanhf_(gi[10 + u] + rg * gh[10 + u]);
                h2[u] = (1.f - zg) * ng + zg * h2[u];
            }
        }
#pragma unroll
        for (int u = 0; u < 5; ++u) hsl[lane * 5 + u] = h2[u];
    }

    // ---- final linear + highway + sigmoid, lanes 0..7 ----
    if (lane < 8) {
        const int m = lane;
        float acc = l1_b[m];
        const float* wrow = l1_w + m * 170;
#pragma unroll
        for (int j = 0; j < 50; ++j) acc += r1l[j] * wrow[j];
#pragma unroll
        for (int j = 0; j < 120; ++j) acc += hsl[j] * wrow[50 + j];
        float z = hw_b[0];
        const float* xb = x + (size_t)b * 1344 + 144 * 8 + m;
#pragma unroll
        for (int wi = 0; wi < 24; ++wi) z += xb[wi * 8] * hw_w[wi];
        out[b * 8 + m] = __builtin_amdgcn_rcpf(1.f + __expf(-(acc + z)));
    }
}

// ---------------------------------------------------------------------------
extern "C" void kernel_launch(void* const* d_in, const int* in_sizes, int n_in,
                              void* d_out, int out_size, void* d_ws, size_t ws_size,
                              hipStream_t stream) {
    const float* x      = (const float*)d_in[0];
    const float* conv_w = (const float*)d_in[1];
    const float* conv_b = (const float*)d_in[2];
    const float* g1_wih = (const float*)d_in[3];
    const float* g1_whh = (const float*)d_in[4];
    const float* g1_bih = (const float*)d_in[5];
    const float* g1_bhh = (const float*)d_in[6];
    const float* gs_wih = (const float*)d_in[7];
    const float* gs_whh = (const float*)d_in[8];
    const float* gs_bih = (const float*)d_in[9];
    const float* gs_bhh = (const float*)d_in[10];
    const float* l1_w   = (const float*)d_in[11];
    const float* l1_b   = (const float*)d_in[12];
    const float* hw_w   = (const float*)d_in[13];
    const float* hw_b   = (const float*)d_in[14];
    float* out = (float*)d_out;

    char* ws = (char*)d_ws;
    unsigned short* c = (unsigned short*)ws;              // 12,902,400 B
    float* gi1g       = (float*)(ws + 12902400);          // 128*24450*4 = 12,518,400 B
    float* gi2g       = (float*)(ws + 25420800);          // 128*2160*4  =  1,105,920 B

    hipLaunchKernelGGL(k1_conv_gemm, dim3(450), dim3(256), 0, stream, x, conv_w, conv_b, c);
    hipLaunchKernelGGL(k_proj,       dim3(128), dim3(384), 0, stream,
                       c, g1_wih, g1_bih, gs_wih, gs_bih, gi1g, gi2g);
    hipLaunchKernelGGL(k_gru,        dim3(128), dim3(64),  0, stream,
                       gi1g, g1_whh, g1_bhh, gi2g, gs_whh, gs_bhh,
                       l1_w, l1_b, x, hw_w, hw_b, out);
}